// Round 1
// baseline (107.441 us; speedup 1.0000x reference)
//
#include <hip/hip_runtime.h>
#include <cmath>

// Problem constants (match reference init)
#define BB   64
#define HH   64
#define WW   64
#define CI   16
#define CO   32
#define KK   3
#define NIN  (KK*KK*CI)   // 144
#define ROWS 4            // rows of output per block

// ---------------------------------------------------------------------------
// Pre-kernel: per-output-channel constants
//   ws[0..31]  = zn[c]   = max(||z[:,c]||, 1e-7)
//   ws[32..63] = cosh(2*sc*r[c])   (sc = sqrt(c) = 1)
//   ws[64..95] = sinh(2*sc*r[c])
// ---------------------------------------------------------------------------
__global__ void hyp_pre_kernel(const float* __restrict__ z,
                               const float* __restrict__ r,
                               float* __restrict__ ws) {
    int c = threadIdx.x;
    if (c < CO) {
        float s = 0.0f;
        for (int k = 0; k < NIN; ++k) {
            float v = z[k * CO + c];
            s = fmaf(v, v, s);
        }
        float zn = fmaxf(sqrtf(s), 1e-7f);
        float tcr = 2.0f * r[c];          // 2 * sc * r, sc = 1
        ws[c]          = zn;
        ws[CO + c]     = coshf(tcr);
        ws[2 * CO + c] = sinhf(tcr);
    }
}

// ---------------------------------------------------------------------------
// Main kernel: one block = (b, 4 output rows, all 64 cols).
// LDS-stages a 6 x 66 x 16 edge-clamped x slab ([6][66][17] padded),
// then each thread computes one pixel: 144x32 fp32 dot + epilogue.
// ---------------------------------------------------------------------------
__global__ __launch_bounds__(256) void hyp_main_kernel(
        const float* __restrict__ x,
        const float* __restrict__ z,
        const float* __restrict__ pre,   // zn / cosh / sinh tables (ws)
        float* __restrict__ out,
        float ratio) {
    // [row -1..+4][w -1..+64][ci], channel dim padded 16->17 to break the
    // 16-float lane stride (would be a 32-way bank conflict otherwise).
    __shared__ float xt[6][66][17];

    const int blk = blockIdx.x;
    const int b  = blk >> 4;            // 16 blocks per image (64 rows / 4)
    const int h0 = (blk & 15) * ROWS;
    const int tid = threadIdx.x;

    // ---- stage x slab: rows h0-1 .. h0+4 clamped, cols -1..64 clamped ----
    for (int l = tid; l < 6 * 66 * CI; l += 256) {
        int rr  = l / (66 * CI);
        int rem = l - rr * (66 * CI);
        int wi  = rem / CI;             // 0..65  -> w = wi-1
        int ci  = rem - wi * CI;
        int hh  = h0 - 1 + rr; hh = hh < 0 ? 0 : (hh > HH - 1 ? HH - 1 : hh);
        int wg  = wi - 1;      wg = wg < 0 ? 0 : (wg > WW - 1 ? WW - 1 : wg);
        xt[rr][wi][ci] = x[(((b * HH) + hh) * WW + wg) * CI + ci];
    }
    __syncthreads();

    const int w   = tid & 63;
    const int row = tid >> 6;           // 0..3

    float acc[CO];
#pragma unroll
    for (int co = 0; co < CO; ++co) acc[co] = 0.0f;
    float s2 = 0.0f;

    // ---- implicit im2col GEMM: k = (kh, kw, ci), z row uniform -> s_load ----
    for (int kh = 0; kh < KK; ++kh) {
        for (int kw = 0; kw < KK; ++kw) {
            const float* zr = z + ((kh * KK + kw) * CI) * CO;
#pragma unroll
            for (int ci = 0; ci < CI; ++ci) {
                float p = xt[row + kh][w + kw][ci];
                s2 = fmaf(p, p, s2);
#pragma unroll
                for (int co = 0; co < CO; ++co)
                    acc[co] = fmaf(p, zr[ci * CO + co], acc[co]);
            }
        }
    }

    // ---- epilogue ----
    // y = ratio * p, projected into the ball if ||y|| > max_norm
    const float max_norm = 0.99999f;            // (1 - 1e-5) / sc, sc = 1
    float yn = ratio * sqrtf(s2);
    float scale = ratio;
    if (yn > max_norm) scale = ratio * (max_norm / fmaxf(yn, 1e-7f));
    float yn2 = scale * scale * s2;
    float lam = 2.0f / fmaxf(1.0f - yn2, 1e-7f);
    float lamm1 = lam - 1.0f;

    float wn2 = 0.0f;
#pragma unroll
    for (int co = 0; co < CO; ++co) {
        float zn = pre[co];
        float ch = pre[CO + co];
        float sh = pre[2 * CO + co];
        float xz = scale * acc[co];
        float arg = lam * (xz / zn) * ch - lamm1 * sh;
        float v = 2.0f * zn * asinhf(arg);      // (2 zn / sc) asinh, sc = 1
        v = 50.0f * tanhf(v * (1.0f / 50.0f));  // CLAMP_F * SMOOTH_F * tanh(v/SF)
        float wv = sinhf(v);                    // sinh(sc v)/sc, sc = 1
        acc[co] = wv;                           // reuse accumulator regs
        wn2 = fmaf(wv, wv, wn2);
    }
    float inv = 1.0f / (1.0f + sqrtf(1.0f + wn2));

    float* op = out + ((((b * HH) + (h0 + row)) * WW + w) * CO);
#pragma unroll
    for (int co = 0; co < CO; co += 4) {
        float4 o;
        o.x = acc[co + 0] * inv;
        o.y = acc[co + 1] * inv;
        o.z = acc[co + 2] * inv;
        o.w = acc[co + 3] * inv;
        *reinterpret_cast<float4*>(op + co) = o;
    }
}

// ---------------------------------------------------------------------------
extern "C" void kernel_launch(void* const* d_in, const int* in_sizes, int n_in,
                              void* d_out, int out_size, void* d_ws, size_t ws_size,
                              hipStream_t stream) {
    const float* x = (const float*)d_in[0];
    const float* z = (const float*)d_in[1];
    const float* r = (const float*)d_in[2];
    float* out = (float*)d_out;
    float* ws  = (float*)d_ws;

    // beta-concatenation ratio: exp(logB(144/2,1/2) - logB(16/2,1/2))
    double lb_n = lgamma(NIN / 2.0) + lgamma(0.5) - lgamma((NIN + 1) / 2.0);
    double lb_c = lgamma(CI  / 2.0) + lgamma(0.5) - lgamma((CI  + 1) / 2.0);
    float ratio = (float)exp(lb_n - lb_c);

    hyp_pre_kernel<<<1, 64, 0, stream>>>(z, r, ws);

    const int blocks = BB * (HH / ROWS);   // 64 * 16 = 1024
    hyp_main_kernel<<<blocks, 256, 0, stream>>>(x, z, ws, out, ratio);
}

// Round 2
// 30.037 us; speedup vs baseline: 3.5770x; 3.5770x over previous
//
#include <hip/hip_runtime.h>
#include <cmath>

#define BB 64
#define HH 64
#define WW 64
#define CI 16
#define CO 32
#define NIN 144           // 3*3*16

typedef __attribute__((ext_vector_type(8))) short s16x8;   // 8 bf16 (4 VGPRs)
typedef __attribute__((ext_vector_type(4))) float f32x4;

// RNE pack of two fp32 -> (lo, hi) bf16 in one u32
__device__ __forceinline__ unsigned pk_bf16(float a, float b) {
    unsigned ua = __float_as_uint(a);
    unsigned ub = __float_as_uint(b);
    ua = (ua + 0x7fffu + ((ua >> 16) & 1u)) >> 16;
    ub = (ub + 0x7fffu + ((ub >> 16) & 1u)) & 0xffff0000u;
    return ua | ub;
}

// ---------------------------------------------------------------------------
// Pre-kernel:
//   ws[0..31]   cosh(2r)/zn      ws[32..63] sinh(2r)     ws[64..95] 2*zn
//   ws+128 ...  12 B-fragments (bf16, exact mfma lane layout), K padded
//               per kh-row to 64 (K'=192), frag f=(kstep s, co-half hf)
// ---------------------------------------------------------------------------
__global__ void hyp_pre(const float* __restrict__ z, const float* __restrict__ r,
                        float* __restrict__ ws) {
    int t = threadIdx.x;
    if (t < CO) {
        float s = 0.f;
        for (int k = 0; k < NIN; ++k) { float v = z[k * CO + t]; s = fmaf(v, v, s); }
        float zn = fmaxf(sqrtf(s), 1e-7f);
        float tc = 2.0f * r[t];
        ws[t]          = coshf(tc) / zn;
        ws[CO + t]     = sinhf(tc);
        ws[2 * CO + t] = 2.0f * zn;
    }
    uint4* fr = (uint4*)(ws + 128);
    for (int idx = t; idx < 12 * 64; idx += blockDim.x) {
        int f = idx >> 6, lane = idx & 63;
        int s = f >> 1, hf = f & 1;
        int co = hf * 16 + (lane & 15);
        unsigned u[4];
#pragma unroll
        for (int jj = 0; jj < 4; ++jj) {
            int kp0 = s * 32 + (lane >> 4) * 8 + jj * 2;
            int row0 = kp0 >> 6, pos0 = kp0 & 63;
            float v0 = (pos0 < 48) ? z[(row0 * 48 + pos0) * CO + co] : 0.f;
            int kp1 = kp0 + 1;
            int row1 = kp1 >> 6, pos1 = kp1 & 63;
            float v1 = (pos1 < 48) ? z[(row1 * 48 + pos1) * CO + co] : 0.f;
            u[jj] = pk_bf16(v0, v1);
        }
        fr[idx] = make_uint4(u[0], u[1], u[2], u[3]);
    }
}

// ---------------------------------------------------------------------------
// Main kernel: block = (b, 4 rows x 64 cols), 4 waves, each wave 4 tiles of
// 16px x 32co via mfma_f32_16x16x32_bf16 (K'=192 -> 6 ksteps x 2 halves).
// ---------------------------------------------------------------------------
__global__ __launch_bounds__(256) void hyp_main(
        const float* __restrict__ x,
        const float* __restrict__ ws,
        float* __restrict__ out,
        float ratio) {
    __shared__ __align__(16) unsigned short xs[6][67][CI];  // bf16 of ratio*x
    __shared__ float qs[6][67];                             // per-cell sum x^2
    __shared__ float lam_ls[4][64];                         // lam * proj_scale
    __shared__ float lam_m1[4][64];                         // lam - 1
    __shared__ float pre_s[96];

    const int tid  = threadIdx.x;
    const int lane = tid & 63;
    const int wid  = tid >> 6;
    const int blk  = blockIdx.x;
    const int b    = blk >> 4;
    const int h0   = (blk & 15) << 2;

    // B-fragments: same for every wave, L2-resident
    s16x8 bf[12];
    {
        const uint4* fp = (const uint4*)(ws + 128);
#pragma unroll
        for (int f = 0; f < 12; ++f)
            bf[f] = __builtin_bit_cast(s16x8, fp[f * 64 + lane]);
    }
    if (tid < 96) pre_s[tid] = ws[tid];

    // ---- stage x slab (rows h0-1..h0+4, cols -1..65, edge-clamped) ----
    const float ratio2 = ratio * ratio;
    for (int cell = tid; cell < 6 * 67; cell += 256) {
        int rr = cell / 67;
        int wi = cell - rr * 67;
        int gh = h0 - 1 + rr; gh = gh < 0 ? 0 : (gh > HH - 1 ? HH - 1 : gh);
        int gw = wi - 1;      gw = gw < 0 ? 0 : (gw > WW - 1 ? WW - 1 : gw);
        const float4* src = (const float4*)(x + ((((b << 6) + gh) << 6) + gw) * CI);
        float4 v0 = src[0], v1 = src[1], v2 = src[2], v3 = src[3];
        float q = 0.f;
        q = fmaf(v0.x, v0.x, q); q = fmaf(v0.y, v0.y, q);
        q = fmaf(v0.z, v0.z, q); q = fmaf(v0.w, v0.w, q);
        q = fmaf(v1.x, v1.x, q); q = fmaf(v1.y, v1.y, q);
        q = fmaf(v1.z, v1.z, q); q = fmaf(v1.w, v1.w, q);
        q = fmaf(v2.x, v2.x, q); q = fmaf(v2.y, v2.y, q);
        q = fmaf(v2.z, v2.z, q); q = fmaf(v2.w, v2.w, q);
        q = fmaf(v3.x, v3.x, q); q = fmaf(v3.y, v3.y, q);
        q = fmaf(v3.z, v3.z, q); q = fmaf(v3.w, v3.w, q);
        uint4 lo, hi;
        lo.x = pk_bf16(v0.x * ratio, v0.y * ratio);
        lo.y = pk_bf16(v0.z * ratio, v0.w * ratio);
        lo.z = pk_bf16(v1.x * ratio, v1.y * ratio);
        lo.w = pk_bf16(v1.z * ratio, v1.w * ratio);
        hi.x = pk_bf16(v2.x * ratio, v2.y * ratio);
        hi.y = pk_bf16(v2.z * ratio, v2.w * ratio);
        hi.z = pk_bf16(v3.x * ratio, v3.y * ratio);
        hi.w = pk_bf16(v3.z * ratio, v3.w * ratio);
        *(uint4*)&xs[rr][wi][0] = lo;
        *(uint4*)&xs[rr][wi][8] = hi;
        qs[rr][wi] = q;
    }
    __syncthreads();

    // ---- per-pixel lambda / projection scale ----
    {
        int pr = tid >> 6;
        int w  = tid & 63;
        float s2 = 0.f;
#pragma unroll
        for (int kh = 0; kh < 3; ++kh)
#pragma unroll
            for (int kw = 0; kw < 3; ++kw)
                s2 += qs[pr + kh][w + kw];
        s2 *= ratio2;
        float yn = sqrtf(s2);
        float se = 1.0f;
        const float mn = 0.99999f;               // (1-1e-5)/sqrt(c)
        if (yn > mn) se = mn / fmaxf(yn, 1e-7f);
        float yn2 = s2 * se * se;
        float lam = 2.0f * __builtin_amdgcn_rcpf(fmaxf(1.0f - yn2, 1e-7f));
        lam_ls[pr][w] = lam * se;
        lam_m1[pr][w] = lam - 1.0f;
    }
    __syncthreads();

    const int col = lane & 15;
    const int g   = lane >> 4;
    const float cz0 = pre_s[col],      cz1 = pre_s[col + 16];
    const float sh0 = pre_s[32 + col], sh1 = pre_s[48 + col];
    const float tz0 = pre_s[64 + col], tz1 = pre_s[80 + col];

    for (int wc = 0; wc < 4; ++wc) {
        f32x4 acc0 = {0.f, 0.f, 0.f, 0.f};
        f32x4 acc1 = {0.f, 0.f, 0.f, 0.f};
#pragma unroll
        for (int s = 0; s < 6; ++s) {
            int kc  = (s & 1) ? 2 : (g >> 1);   // cell (kw) within the kh row
            int ci0 = (g & 1) * 8;
            s16x8 a = {};
            if (!(s & 1) || g < 2)              // zero-pad tail 16 of each row
                a = *(const s16x8*)&xs[wid + (s >> 1)][wc * 16 + col + kc][ci0];
            acc0 = __builtin_amdgcn_mfma_f32_16x16x32_bf16(a, bf[2 * s],     acc0, 0, 0, 0);
            acc1 = __builtin_amdgcn_mfma_f32_16x16x32_bf16(a, bf[2 * s + 1], acc1, 0, 0, 0);
        }
        float* orow = out + ((((b << 6) + h0 + wid) << 6) + wc * 16) * CO;
#pragma unroll
        for (int i = 0; i < 4; ++i) {
            int pw = g * 4 + i;                 // pixel (w) within the 16-tile
            float ls = lam_ls[wid][wc * 16 + pw];
            float lm = lam_m1[wid][wc * 16 + pw];
            float a0 = fmaf(ls * acc0[i], cz0, -(lm * sh0));
            float a1 = fmaf(ls * acc1[i], cz1, -(lm * sh1));
            // v = 2*zn*asinh(arg)
            float ax0 = fabsf(a0), ax1 = fabsf(a1);
            float v0 = copysignf(tz0 * __logf(ax0 + __builtin_amdgcn_sqrtf(fmaf(ax0, ax0, 1.f))), a0);
            float v1 = copysignf(tz1 * __logf(ax1 + __builtin_amdgcn_sqrtf(fmaf(ax1, ax1, 1.f))), a1);
            // v = 50*tanh(v/50)
            float e0 = __expf(fabsf(v0) * 0.04f);   // exp(2|v|/50)
            float e1 = __expf(fabsf(v1) * 0.04f);
            float t0 = copysignf(1.f - 2.f * __builtin_amdgcn_rcpf(e0 + 1.f), v0) * 50.f;
            float t1 = copysignf(1.f - 2.f * __builtin_amdgcn_rcpf(e1 + 1.f), v1) * 50.f;
            // w = sinh(v)
            float s0 = __expf(t0);
            float s1 = __expf(t1);
            float w0v = 0.5f * (s0 - __builtin_amdgcn_rcpf(s0));
            float w1v = 0.5f * (s1 - __builtin_amdgcn_rcpf(s1));
            // wn2 across all 32 co (16 lanes x 2 halves)
            float wsq = fmaf(w0v, w0v, w1v * w1v);
            wsq += __shfl_xor(wsq, 1, 16);
            wsq += __shfl_xor(wsq, 2, 16);
            wsq += __shfl_xor(wsq, 4, 16);
            wsq += __shfl_xor(wsq, 8, 16);
            float inv = __builtin_amdgcn_rcpf(1.f + __builtin_amdgcn_sqrtf(1.f + wsq));
            orow[pw * CO + col]      = w0v * inv;
            orow[pw * CO + 16 + col] = w1v * inv;
        }
    }
}

// ---------------------------------------------------------------------------
extern "C" void kernel_launch(void* const* d_in, const int* in_sizes, int n_in,
                              void* d_out, int out_size, void* d_ws, size_t ws_size,
                              hipStream_t stream) {
    const float* x = (const float*)d_in[0];
    const float* z = (const float*)d_in[1];
    const float* r = (const float*)d_in[2];
    float* out = (float*)d_out;
    float* ws  = (float*)d_ws;

    double lb_n = lgamma(NIN / 2.0) + lgamma(0.5) - lgamma((NIN + 1) / 2.0);
    double lb_c = lgamma(CI  / 2.0) + lgamma(0.5) - lgamma((CI  + 1) / 2.0);
    float ratio = (float)exp(lb_n - lb_c);

    hyp_pre<<<1, 256, 0, stream>>>(z, r, ws);
    hyp_main<<<BB * (HH / 4), 256, 0, stream>>>(x, ws, out, ratio);
}